// Round 13
// baseline (387.433 us; speedup 1.0000x reference)
//
#include <hip/hip_runtime.h>
#include <hip/hip_bf16.h>
#include <math.h>

typedef __attribute__((ext_vector_type(4))) float fx4;
typedef __attribute__((ext_vector_type(8))) short bx8;   // 8 bf16 (one MFMA A/B fragment)
typedef __attribute__((ext_vector_type(4))) short bx4;   // 4 bf16

#define DEV static __device__ __forceinline__
#define N_NODES 20000
#define N_EDGES 640000

DEV unsigned short f2bf(float f){
  __hip_bfloat16 h = __float2bfloat16(f);        // RNE hardware cvt
  return *(unsigned short*)&h;
}
DEV float bf2f(unsigned short h){
  union { float f; unsigned u; } a; a.u = ((unsigned)h) << 16;
  return a.f;
}
DEV float fast_tanh(float x){
  float t = __expf(2.0f * x);
  return 1.0f - 2.0f * __builtin_amdgcn_rcpf(t + 1.0f);
}
DEV bx8 cvt8(fx4 a, fx4 b){
  bx8 r;
  r[0]=(short)f2bf(a[0]); r[1]=(short)f2bf(a[1]); r[2]=(short)f2bf(a[2]); r[3]=(short)f2bf(a[3]);
  r[4]=(short)f2bf(b[0]); r[5]=(short)f2bf(b[1]); r[6]=(short)f2bf(b[2]); r[7]=(short)f2bf(b[3]);
  return r;
}
// T2 XOR swizzle: pitch 128 elems (256B), col ^ ((row&7)<<3); 16B-window preserving
DEV int swz(int r, int c){ return r*128 + (c ^ ((r & 7) << 3)); }

// ---------------- K0: ALL weight prep in one launch ----------------
// Fragment-packed layout: P[((nblk*KS + ks)*64 + lane)*8 + j]
//   = W[(ks*32 + (lane>>4)*8 + j)*N + (nblk*16 + (lane&15))]
__global__ __launch_bounds__(256)
void prep_all_kernel(const float* __restrict__ Wn, const float* __restrict__ Wd,
                     const float* __restrict__ We, const float* __restrict__ Wc,
                     const float* __restrict__ be,
                     unsigned short* __restrict__ WnP, unsigned short* __restrict__ WdP,
                     unsigned short* __restrict__ WctP, unsigned short* __restrict__ WeffP,
                     float* __restrict__ ceff)
{
  int t = blockIdx.x * 256 + threadIdx.x;
  if (t < 32768){
    int i=t, j=i&7, lane=(i>>3)&63, ks=(i>>9)&7, nblk=i>>12;
    WnP[i] = f2bf(Wn[(ks*32 + (lane>>4)*8 + j)*128 + nblk*16 + (lane&15)]);
  } else if (t < 40960){
    int i=t-32768, j=i&7, lane=(i>>3)&63, ks=(i>>9)&1, nblk=i>>10;
    WdP[i] = f2bf(Wd[(ks*32 + (lane>>4)*8 + j)*128 + nblk*16 + (lane&15)]);
  } else if (t < 73728){
    int i=t-40960, j=i&7, lane=(i>>3)&63, ks=(i>>9)&3, nblk=i>>11;
    WctP[i] = f2bf(Wc[(ks*32 + (lane>>4)*8 + j)*256 + nblk*16 + (lane&15)]);
  } else if (t < 106496){
    int i=t-73728, j=i&7, lane=(i>>3)&63, ks=(i>>9)&3, nblk=i>>11;
    int k = ks*32 + (lane>>4)*8 + j;
    int n = nblk*16 + (lane&15);
    float s = 0.f;
    for (int h = 0; h < 128; ++h)
      s += We[k*128 + h] * Wc[(128+h)*256 + n];      // Weff = We @ Wc_bot
    WeffP[i] = f2bf(s);
  } else if (t < 106752){
    int n = t - 106496;
    float s = 0.f;
    for (int h = 0; h < 128; ++h)
      s += be[h] * Wc[(128+h)*256 + n];              // ceff = be @ Wc_bot
    ceff[n] = s;
  }
}

// ---------------- counting sort by dst ----------------
__global__ __launch_bounds__(256)
void hist_kernel(const int* __restrict__ dst, int* __restrict__ cnt)
{
  int e = blockIdx.x * 256 + threadIdx.x;
  if (e < N_EDGES) atomicAdd(&cnt[dst[e]], 1);
}

// hierarchical exclusive scan: A (20 blocks local) -> B (scan 20 sums) -> C (add offsets)
__global__ __launch_bounds__(1024)
void scanA_kernel(const int* __restrict__ cnt, int* __restrict__ fill, int* __restrict__ bsum)
{
  __shared__ int wsum[16];
  const int t = threadIdx.x, lane = t & 63, w = t >> 6;
  int i = blockIdx.x * 1024 + t;
  int v = (i < N_NODES) ? cnt[i] : 0;
  int x = v;
#pragma unroll
  for (int s = 1; s < 64; s <<= 1){
    int u = __shfl_up(x, s, 64);
    if (lane >= s) x += u;
  }
  if (lane == 63) wsum[w] = x;
  __syncthreads();
  if (w == 0 && lane < 16){
    int y = wsum[lane];
#pragma unroll
    for (int s = 1; s < 16; s <<= 1){
      int u = __shfl_up(y, s, 64);
      if (lane >= s) y += u;
    }
    wsum[lane] = y;
  }
  __syncthreads();
  int wbase = (w == 0) ? 0 : wsum[w-1];
  int excl = wbase + x - v;
  if (i < N_NODES) fill[i] = excl;
  if (t == 1023) bsum[blockIdx.x] = excl + v;
}

__global__ __launch_bounds__(64)
void scanB_kernel(int* __restrict__ bsum)
{
  int lane = threadIdx.x;
  int v = (lane < 20) ? bsum[lane] : 0;
  int x = v;
#pragma unroll
  for (int s = 1; s < 32; s <<= 1){
    int u = __shfl_up(x, s, 64);
    if (lane >= s) x += u;
  }
  if (lane < 20) bsum[lane] = x - v;   // exclusive
}

__global__ __launch_bounds__(1024)
void scanC_kernel(int* __restrict__ fill, const int* __restrict__ bsum)
{
  int i = blockIdx.x * 1024 + threadIdx.x;
  if (i < N_NODES) fill[i] += bsum[blockIdx.x];
}

// scatter: perm[pos]=e ; sd[pos] = (src[e]<<16) | dst[e]   (both < 2^16)
__global__ __launch_bounds__(256)
void scatter_kernel(const int* __restrict__ dst, const int* __restrict__ src,
                    int* __restrict__ fill,
                    int* __restrict__ perm, int* __restrict__ sd)
{
  int e = blockIdx.x * 256 + threadIdx.x;
  if (e < N_EDGES){
    int d = dst[e];
    int pos = atomicAdd(&fill[d], 1);
    perm[pos] = e;
    sd[pos] = (src[e] << 16) | d;
  }
}

// ---------------- K1: node_proj = bf16(node_h @ W_node + b_node)  [20000][128] ----------------
__global__ __launch_bounds__(64)
void node_proj_kernel(const float* __restrict__ node_h, const unsigned short* __restrict__ WnP,
                      const float* __restrict__ b_node, unsigned short* __restrict__ npj)
{
  __shared__ unsigned short sN[16 * 264];
  const int lane = threadIdx.x;
  const int lr = lane & 15, lq = lane >> 4;
  const long r0 = (long)blockIdx.x * 16;

  const fx4* g = (const fx4*)(node_h + r0 * 256);
#pragma unroll
  for (int i = 0; i < 16; ++i){
    int idx = lane + 64 * i;
    int r = idx >> 6, c4 = idx & 63;
    fx4 v = g[idx];
    bx4 b;
    b[0]=(short)f2bf(v[0]); b[1]=(short)f2bf(v[1]); b[2]=(short)f2bf(v[2]); b[3]=(short)f2bf(v[3]);
    *(bx4*)&sN[r*264 + c4*4] = b;
  }
  __syncthreads();

  fx4 acc[8];
#pragma unroll
  for (int n = 0; n < 8; ++n) acc[n] = (fx4){0.f,0.f,0.f,0.f};
#pragma unroll
  for (int ks = 0; ks < 8; ++ks){
    bx8 a = *(const bx8*)&sN[lr*264 + ks*32 + lq*8];
#pragma unroll
    for (int n = 0; n < 8; ++n){
      bx8 b = *(const bx8*)&WnP[((n*8 + ks)*64 + lane)*8];
      acc[n] = __builtin_amdgcn_mfma_f32_16x16x32_bf16(a, b, acc[n], 0, 0, 0);
    }
  }
#pragma unroll
  for (int n = 0; n < 8; ++n){
    float bias = b_node[n*16 + lr];
#pragma unroll
    for (int j = 0; j < 4; ++j)
      npj[(r0 + lq*4 + j)*128 + n*16 + lr] = f2bf(acc[n][j] + bias);
  }
}

// ---------------- K2: fused pipeline over SORTED edges, 64 edges/block, 1 barrier ----------------
// out = tanh( m1 @ Wc_top + edge @ Weff + ceff ), Weff = We@Wc_bot (prep).
// sd[] packs (src<<16)|dst so src needs NO dependent gather.
// R13: sX/sE pitch 136 -> 128 with T2 XOR swizzle (col ^ ((row&7)<<3)); LDS 32768B
// -> exactly 5 blocks/CU (160KiB), __launch_bounds__(256,5). Regs 64V+32A=96 <= 102.
// Wave w owns rows [16w,16w+16): issue dist loads first, then npj gather (from sd),
// then edge rows; dist GEMM with b_dist folded -> sX; m1 in-place; sE staging.
// ONE barrier; two-half comb (acc[4][2], fully unrolled); tanh (rcp); register segsum.
__global__ __launch_bounds__(256, 5)
void edge_kernel(const float* __restrict__ edge_h, const float* __restrict__ dist,
                 const int* __restrict__ perm, const int* __restrict__ sd,
                 const unsigned short* __restrict__ npj,
                 const unsigned short* __restrict__ WdP, const float* __restrict__ b_dist,
                 const unsigned short* __restrict__ WctP, const unsigned short* __restrict__ WeffP,
                 const float* __restrict__ ceff,
                 float* __restrict__ hacc)
{
  __shared__ unsigned short sX[4][16*128];   // m1 (bf16), per-wave chunk, swizzled
  __shared__ unsigned short sE[4][16*128];   // edge rows (bf16), per-wave chunk, swizzled

  const int tid  = threadIdx.x;
  const int w    = tid >> 6;
  const int lane = tid & 63;
  const int lr   = lane & 15;
  const int lq   = lane >> 4;
  const int c32  = lane & 31;              // column chunk (4 elems) for chunk-layout ops
  const long e0  = (long)blockIdx.x * 64;

  // ---- ids: sd gives (src,dst) for all 64 tile rows in one coalesced load ----
  const int vSD  = sd[e0 + lane];            // row 'lane' of tile
  const int vDst = vSD & 0xffff;
  int vPerm = 0;
  if (lane < 16) vPerm = perm[e0 + w*16 + lane];
  const int pRow = __shfl(vPerm, lr);        // edge index of this wave's row lr

  // ---- issue dist loads (consumed first by the GEMM) ----
  const float* dp = dist + (long)pRow*64 + lq*8;
  fx4 d0 = *(const fx4*)(dp);
  fx4 d1 = *(const fx4*)(dp + 4);
  fx4 d2 = *(const fx4*)(dp + 32);
  fx4 d3 = *(const fx4*)(dp + 36);

  // ---- issue npj gather (src from sd; no dependent hop) ----
  bx4 rN[8];
#pragma unroll
  for (int i = 0; i < 8; ++i){
    int r = (lane >> 5) + 2*i;
    int s = __shfl(vSD, w*16 + r) >> 16;
    rN[i] = *(const bx4*)(npj + (long)s*128 + c32*4);
  }

  // ---- issue edge-row loads (consumed last -> longest latency slack) ----
  fx4 rE[8];
#pragma unroll
  for (int i = 0; i < 8; ++i){
    int r = (lane >> 5) + 2*i;
    int p = __shfl(vPerm, r);
    rE[i] = *(const fx4*)(edge_h + (long)p*128 + c32*4);
  }

  // ---- dist GEMM: M=16 (own rows), N=128, K=64; bias folded into acc init ----
  {
    bx8 a0 = cvt8(d0, d1);
    bx8 a1 = cvt8(d2, d3);
    fx4 facc[8];
#pragma unroll
    for (int n = 0; n < 8; ++n){
      float bdv = b_dist[n*16 + lr];
      facc[n] = (fx4){bdv, bdv, bdv, bdv};
    }
#pragma unroll
    for (int n = 0; n < 8; ++n){
      bx8 b = *(const bx8*)&WdP[((n*2 + 0)*64 + lane)*8];
      facc[n] = __builtin_amdgcn_mfma_f32_16x16x32_bf16(a0, b, facc[n], 0, 0, 0);
    }
#pragma unroll
    for (int n = 0; n < 8; ++n){
      bx8 b = *(const bx8*)&WdP[((n*2 + 1)*64 + lane)*8];
      facc[n] = __builtin_amdgcn_mfma_f32_16x16x32_bf16(a1, b, facc[n], 0, 0, 0);
    }
#pragma unroll
    for (int n = 0; n < 8; ++n)
#pragma unroll
      for (int j = 0; j < 4; ++j)
        sX[w][swz(lq*4 + j, n*16 + lr)] = f2bf(facc[n][j]);
  }

  // ---- m1 in-place: sX = npj[src] * sX  (own rows, same-wave dep) ----
#pragma unroll
  for (int i = 0; i < 8; ++i){
    int r = (lane >> 5) + 2*i;
    int xi = swz(r, c32*4);
    bx4 dp4 = *(const bx4*)&sX[w][xi];
    bx4 o;
#pragma unroll
    for (int k = 0; k < 4; ++k)
      o[k] = (short)f2bf( bf2f((unsigned short)rN[i][k]) * bf2f((unsigned short)dp4[k]) );
    *(bx4*)&sX[w][xi] = o;
  }

  // ---- stage edge rows bf16 -> sE (rE dies here) ----
#pragma unroll
  for (int i = 0; i < 8; ++i){
    int r = (lane >> 5) + 2*i;
    bx4 cv;
    cv[0]=(short)f2bf(rE[i][0]); cv[1]=(short)f2bf(rE[i][1]);
    cv[2]=(short)f2bf(rE[i][2]); cv[3]=(short)f2bf(rE[i][3]);
    *(bx4*)&sE[w][swz(r, c32*4)] = cv;
  }
  __syncthreads();   // the ONLY barrier: sX + sE complete across all waves

  // ---- segsum head mask (hoisted, reused by both halves) ----
  int up = __shfl_up(vDst, 1);
  bool head = (lane == 0) || (up != vDst);
  const unsigned long long mhead = __ballot(head);

  // ---- comb GEMM in two 32-col halves: cols [64w+32h, +32), K = 128(m1)+128(edge) ----
#pragma unroll
  for (int h = 0; h < 2; ++h){
    fx4 acc[4][2];
#pragma unroll
    for (int rt = 0; rt < 4; ++rt)
#pragma unroll
      for (int n = 0; n < 2; ++n) acc[rt][n] = (fx4){0.f,0.f,0.f,0.f};
#pragma unroll
    for (int ks = 0; ks < 4; ++ks){
      bx8 a[4], b[2];
#pragma unroll
      for (int rt = 0; rt < 4; ++rt)
        a[rt] = *(const bx8*)&sX[rt][swz(lr, ks*32 + lq*8)];
#pragma unroll
      for (int n = 0; n < 2; ++n)
        b[n] = *(const bx8*)&WctP[(((4*w + 2*h + n)*4 + ks)*64 + lane)*8];
#pragma unroll
      for (int rt = 0; rt < 4; ++rt)
#pragma unroll
        for (int n = 0; n < 2; ++n)
          acc[rt][n] = __builtin_amdgcn_mfma_f32_16x16x32_bf16(a[rt], b[n], acc[rt][n], 0, 0, 0);
    }
#pragma unroll
    for (int ks = 0; ks < 4; ++ks){
      bx8 a[4], b[2];
#pragma unroll
      for (int rt = 0; rt < 4; ++rt)
        a[rt] = *(const bx8*)&sE[rt][swz(lr, ks*32 + lq*8)];
#pragma unroll
      for (int n = 0; n < 2; ++n)
        b[n] = *(const bx8*)&WeffP[(((4*w + 2*h + n)*4 + ks)*64 + lane)*8];
#pragma unroll
      for (int rt = 0; rt < 4; ++rt)
#pragma unroll
        for (int n = 0; n < 2; ++n)
          acc[rt][n] = __builtin_amdgcn_mfma_f32_16x16x32_bf16(a[rt], b[n], acc[rt][n], 0, 0, 0);
    }

    // ---- + ceff, tanh ----
    float ce0 = ceff[(4*w + 2*h + 0)*16 + lr];
    float ce1 = ceff[(4*w + 2*h + 1)*16 + lr];
#pragma unroll
    for (int rt = 0; rt < 4; ++rt)
#pragma unroll
      for (int j = 0; j < 4; ++j){
        acc[rt][0][j] = fast_tanh(acc[rt][0][j] + ce0);
        acc[rt][1][j] = fast_tanh(acc[rt][1][j] + ce1);
      }

    // ---- register segmented column-sum over dst-runs (this half's 32 cols) ----
    unsigned long long m = mhead;
    while (m){
      int lo = __ffsll((unsigned long long)m) - 1;
      m &= m - 1;
      int hi = m ? (__ffsll((unsigned long long)m) - 1) : 64;
      int d  = __shfl(vDst, lo);
      float s0 = 0.f, s1 = 0.f;
#pragma unroll
      for (int rt = 0; rt < 4; ++rt)
#pragma unroll
        for (int j = 0; j < 4; ++j){
          int row = rt*16 + lq*4 + j;
          float msk = (row >= lo && row < hi) ? 1.f : 0.f;
          s0 += msk * acc[rt][0][j];
          s1 += msk * acc[rt][1][j];
        }
      s0 += __shfl_xor(s0, 16); s0 += __shfl_xor(s0, 32);
      s1 += __shfl_xor(s1, 16); s1 += __shfl_xor(s1, 32);
      if (lq < 2){
        float v = (lq == 0) ? s0 : s1;
        float* p = &hacc[(long)d*256 + (4*w + 2*h + lq)*16 + lr];
        if (lo == 0 || hi == 64) atomicAdd(p, v);   // run may extend past tile
        else                     *p = v;            // tile exclusively owns d
      }
    }
  }
}

// ---------------- K3: in-place row L2-normalize of d_out [20000][256] ----------------
__global__ __launch_bounds__(256)
void norm_kernel(float* __restrict__ h)
{
  int row  = blockIdx.x * 4 + (threadIdx.x >> 6);
  int lane = threadIdx.x & 63;
  fx4 v = *(const fx4*)&h[(long)row*256 + lane*4];
  float s = v[0]*v[0] + v[1]*v[1] + v[2]*v[2] + v[3]*v[3];
#pragma unroll
  for (int off = 32; off > 0; off >>= 1) s += __shfl_xor(s, off);
  float inv = (s > 0.f) ? 1.0f / sqrtf(s) : 0.f;
  v[0]*=inv; v[1]*=inv; v[2]*=inv; v[3]*=inv;
  *(fx4*)&h[(long)row*256 + lane*4] = v;
}

extern "C" void kernel_launch(void* const* d_in, const int* in_sizes, int n_in,
                              void* d_out, int out_size, void* d_ws, size_t ws_size,
                              hipStream_t stream)
{
  const float* node_h = (const float*)d_in[0];
  const float* edge_h = (const float*)d_in[1];
  const float* dist   = (const float*)d_in[2];
  const int*   src    = (const int*)d_in[3];
  const int*   dst    = (const int*)d_in[4];
  const float* W_node = (const float*)d_in[5];
  const float* b_node = (const float*)d_in[6];
  const float* W_edge = (const float*)d_in[7];
  const float* b_edge = (const float*)d_in[8];
  const float* W_dist = (const float*)d_in[9];
  const float* b_dist = (const float*)d_in[10];
  const float* W_comb = (const float*)d_in[11];

  char* ws = (char*)d_ws;
  unsigned short* npj   = (unsigned short*)ws;                  // 5,120,000
  unsigned short* WnP   = (unsigned short*)(ws + 5120000);      // +65,536
  unsigned short* WdP   = (unsigned short*)(ws + 5185536);      // +16,384
  unsigned short* WctP  = (unsigned short*)(ws + 5201920);      // +65,536
  unsigned short* WeffP = (unsigned short*)(ws + 5267456);      // +65,536
  float*          ceff  = (float*)(ws + 5332992);               // +1,024
  int* cnt  = (int*)(ws + 5334016);                             // +80,000
  int* fill = (int*)(ws + 5414016);                             // +80,000
  int* perm = (int*)(ws + 5494016);                             // +2,560,000
  int* sd   = (int*)(ws + 8054016);                             // +2,560,000
  int* bsum = (int*)(ws + 10614016);                            // +128 -> 10,614,144 B

  float* hacc = (float*)d_out;

  hipMemsetAsync(hacc, 0, (size_t)N_NODES * 256 * sizeof(float), stream);
  hipMemsetAsync(cnt, 0, (size_t)N_NODES * sizeof(int), stream);

  prep_all_kernel<<<417, 256, 0, stream>>>(W_node, W_dist, W_edge, W_comb, b_edge,
                                           WnP, WdP, WctP, WeffP, ceff);
  hist_kernel<<<2500, 256, 0, stream>>>(dst, cnt);
  scanA_kernel<<<20, 1024, 0, stream>>>(cnt, fill, bsum);
  scanB_kernel<<<1, 64, 0, stream>>>(bsum);
  scanC_kernel<<<20, 1024, 0, stream>>>(fill, bsum);
  scatter_kernel<<<2500, 256, 0, stream>>>(dst, src, fill, perm, sd);
  node_proj_kernel<<<1250, 64, 0, stream>>>(node_h, WnP, b_node, npj);
  edge_kernel<<<10000, 256, 0, stream>>>(edge_h, dist, perm, sd, npj,
                                         WdP, b_dist, WctP, WeffP, ceff, hacc);
  norm_kernel<<<5000, 256, 0, stream>>>(hacc);
}

// Round 14
// 347.714 us; speedup vs baseline: 1.1142x; 1.1142x over previous
//
#include <hip/hip_runtime.h>
#include <hip/hip_bf16.h>
#include <math.h>

typedef __attribute__((ext_vector_type(4))) float fx4;
typedef __attribute__((ext_vector_type(8))) short bx8;   // 8 bf16 (one MFMA A/B fragment)
typedef __attribute__((ext_vector_type(4))) short bx4;   // 4 bf16

#define DEV static __device__ __forceinline__
#define N_NODES 20000
#define N_EDGES 640000

DEV unsigned short f2bf(float f){
  __hip_bfloat16 h = __float2bfloat16(f);        // RNE hardware cvt
  return *(unsigned short*)&h;
}
DEV float bf2f(unsigned short h){
  union { float f; unsigned u; } a; a.u = ((unsigned)h) << 16;
  return a.f;
}
DEV float fast_tanh(float x){
  float t = __expf(2.0f * x);
  return 1.0f - 2.0f * __builtin_amdgcn_rcpf(t + 1.0f);
}
DEV bx8 cvt8(fx4 a, fx4 b){
  bx8 r;
  r[0]=(short)f2bf(a[0]); r[1]=(short)f2bf(a[1]); r[2]=(short)f2bf(a[2]); r[3]=(short)f2bf(a[3]);
  r[4]=(short)f2bf(b[0]); r[5]=(short)f2bf(b[1]); r[6]=(short)f2bf(b[2]); r[7]=(short)f2bf(b[3]);
  return r;
}
// T2 XOR swizzle: pitch 128 elems (256B), col ^ ((row&7)<<3); 16B-window preserving
DEV int swz(int r, int c){ return r*128 + (c ^ ((r & 7) << 3)); }

// ---------------- K0: ALL weight prep in one launch ----------------
// Fragment-packed layout: P[((nblk*KS + ks)*64 + lane)*8 + j]
//   = W[(ks*32 + (lane>>4)*8 + j)*N + (nblk*16 + (lane&15))]
__global__ __launch_bounds__(256)
void prep_all_kernel(const float* __restrict__ Wn, const float* __restrict__ Wd,
                     const float* __restrict__ We, const float* __restrict__ Wc,
                     const float* __restrict__ be,
                     unsigned short* __restrict__ WnP, unsigned short* __restrict__ WdP,
                     unsigned short* __restrict__ WctP, unsigned short* __restrict__ WeffP,
                     float* __restrict__ ceff)
{
  int t = blockIdx.x * 256 + threadIdx.x;
  if (t < 32768){
    int i=t, j=i&7, lane=(i>>3)&63, ks=(i>>9)&7, nblk=i>>12;
    WnP[i] = f2bf(Wn[(ks*32 + (lane>>4)*8 + j)*128 + nblk*16 + (lane&15)]);
  } else if (t < 40960){
    int i=t-32768, j=i&7, lane=(i>>3)&63, ks=(i>>9)&1, nblk=i>>10;
    WdP[i] = f2bf(Wd[(ks*32 + (lane>>4)*8 + j)*128 + nblk*16 + (lane&15)]);
  } else if (t < 73728){
    int i=t-40960, j=i&7, lane=(i>>3)&63, ks=(i>>9)&3, nblk=i>>11;
    WctP[i] = f2bf(Wc[(ks*32 + (lane>>4)*8 + j)*256 + nblk*16 + (lane&15)]);
  } else if (t < 106496){
    int i=t-73728, j=i&7, lane=(i>>3)&63, ks=(i>>9)&3, nblk=i>>11;
    int k = ks*32 + (lane>>4)*8 + j;
    int n = nblk*16 + (lane&15);
    float s = 0.f;
    for (int h = 0; h < 128; ++h)
      s += We[k*128 + h] * Wc[(128+h)*256 + n];      // Weff = We @ Wc_bot
    WeffP[i] = f2bf(s);
  } else if (t < 106752){
    int n = t - 106496;
    float s = 0.f;
    for (int h = 0; h < 128; ++h)
      s += be[h] * Wc[(128+h)*256 + n];              // ceff = be @ Wc_bot
    ceff[n] = s;
  }
}

// ---------------- counting sort by dst ----------------
__global__ __launch_bounds__(256)
void hist_kernel(const int* __restrict__ dst, int* __restrict__ cnt)
{
  int e = blockIdx.x * 256 + threadIdx.x;
  if (e < N_EDGES) atomicAdd(&cnt[dst[e]], 1);
}

// hierarchical exclusive scan: A (20 blocks local) -> B (scan 20 sums) -> C (add offsets)
__global__ __launch_bounds__(1024)
void scanA_kernel(const int* __restrict__ cnt, int* __restrict__ fill, int* __restrict__ bsum)
{
  __shared__ int wsum[16];
  const int t = threadIdx.x, lane = t & 63, w = t >> 6;
  int i = blockIdx.x * 1024 + t;
  int v = (i < N_NODES) ? cnt[i] : 0;
  int x = v;
#pragma unroll
  for (int s = 1; s < 64; s <<= 1){
    int u = __shfl_up(x, s, 64);
    if (lane >= s) x += u;
  }
  if (lane == 63) wsum[w] = x;
  __syncthreads();
  if (w == 0 && lane < 16){
    int y = wsum[lane];
#pragma unroll
    for (int s = 1; s < 16; s <<= 1){
      int u = __shfl_up(y, s, 64);
      if (lane >= s) y += u;
    }
    wsum[lane] = y;
  }
  __syncthreads();
  int wbase = (w == 0) ? 0 : wsum[w-1];
  int excl = wbase + x - v;
  if (i < N_NODES) fill[i] = excl;
  if (t == 1023) bsum[blockIdx.x] = excl + v;
}

__global__ __launch_bounds__(64)
void scanB_kernel(int* __restrict__ bsum)
{
  int lane = threadIdx.x;
  int v = (lane < 20) ? bsum[lane] : 0;
  int x = v;
#pragma unroll
  for (int s = 1; s < 32; s <<= 1){
    int u = __shfl_up(x, s, 64);
    if (lane >= s) x += u;
  }
  if (lane < 20) bsum[lane] = x - v;   // exclusive
}

__global__ __launch_bounds__(1024)
void scanC_kernel(int* __restrict__ fill, const int* __restrict__ bsum)
{
  int i = blockIdx.x * 1024 + threadIdx.x;
  if (i < N_NODES) fill[i] += bsum[blockIdx.x];
}

// scatter: perm[pos]=e ; sd[pos] = (src[e]<<16) | dst[e]   (both < 2^16)
__global__ __launch_bounds__(256)
void scatter_kernel(const int* __restrict__ dst, const int* __restrict__ src,
                    int* __restrict__ fill,
                    int* __restrict__ perm, int* __restrict__ sd)
{
  int e = blockIdx.x * 256 + threadIdx.x;
  if (e < N_EDGES){
    int d = dst[e];
    int pos = atomicAdd(&fill[d], 1);
    perm[pos] = e;
    sd[pos] = (src[e] << 16) | d;
  }
}

// ---------------- K1: node_proj = bf16(node_h @ W_node + b_node)  [20000][128] ----------------
__global__ __launch_bounds__(64)
void node_proj_kernel(const float* __restrict__ node_h, const unsigned short* __restrict__ WnP,
                      const float* __restrict__ b_node, unsigned short* __restrict__ npj)
{
  __shared__ unsigned short sN[16 * 264];
  const int lane = threadIdx.x;
  const int lr = lane & 15, lq = lane >> 4;
  const long r0 = (long)blockIdx.x * 16;

  const fx4* g = (const fx4*)(node_h + r0 * 256);
#pragma unroll
  for (int i = 0; i < 16; ++i){
    int idx = lane + 64 * i;
    int r = idx >> 6, c4 = idx & 63;
    fx4 v = g[idx];
    bx4 b;
    b[0]=(short)f2bf(v[0]); b[1]=(short)f2bf(v[1]); b[2]=(short)f2bf(v[2]); b[3]=(short)f2bf(v[3]);
    *(bx4*)&sN[r*264 + c4*4] = b;
  }
  __syncthreads();

  fx4 acc[8];
#pragma unroll
  for (int n = 0; n < 8; ++n) acc[n] = (fx4){0.f,0.f,0.f,0.f};
#pragma unroll
  for (int ks = 0; ks < 8; ++ks){
    bx8 a = *(const bx8*)&sN[lr*264 + ks*32 + lq*8];
#pragma unroll
    for (int n = 0; n < 8; ++n){
      bx8 b = *(const bx8*)&WnP[((n*8 + ks)*64 + lane)*8];
      acc[n] = __builtin_amdgcn_mfma_f32_16x16x32_bf16(a, b, acc[n], 0, 0, 0);
    }
  }
#pragma unroll
  for (int n = 0; n < 8; ++n){
    float bias = b_node[n*16 + lr];
#pragma unroll
    for (int j = 0; j < 4; ++j)
      npj[(r0 + lq*4 + j)*128 + n*16 + lr] = f2bf(acc[n][j] + bias);
  }
}

// ---------------- K2: fused pipeline over SORTED edges, 64 edges/block, 1 barrier ----------------
// out = tanh( m1 @ Wc_top + edge @ Weff + ceff ), Weff = We@Wc_bot (prep).
// sd[] packs (src<<16)|dst so src needs NO dependent gather.
// R14: pitch-128 XOR swizzle (LDS 32768B) with __launch_bounds__(256,4) — the compiler
// keeps the natural 64V+32A=96 regs (no squeeze/spill, R13 lesson) and the HW packs
// 5 blocks/CU opportunistically (LDS 5x32KB=160KB, regs 5x96=480<=512).
__global__ __launch_bounds__(256, 4)
void edge_kernel(const float* __restrict__ edge_h, const float* __restrict__ dist,
                 const int* __restrict__ perm, const int* __restrict__ sd,
                 const unsigned short* __restrict__ npj,
                 const unsigned short* __restrict__ WdP, const float* __restrict__ b_dist,
                 const unsigned short* __restrict__ WctP, const unsigned short* __restrict__ WeffP,
                 const float* __restrict__ ceff,
                 float* __restrict__ hacc)
{
  __shared__ unsigned short sX[4][16*128];   // m1 (bf16), per-wave chunk, swizzled
  __shared__ unsigned short sE[4][16*128];   // edge rows (bf16), per-wave chunk, swizzled

  const int tid  = threadIdx.x;
  const int w    = tid >> 6;
  const int lane = tid & 63;
  const int lr   = lane & 15;
  const int lq   = lane >> 4;
  const int c32  = lane & 31;              // column chunk (4 elems) for chunk-layout ops
  const long e0  = (long)blockIdx.x * 64;

  // ---- ids: sd gives (src,dst) for all 64 tile rows in one coalesced load ----
  const int vSD  = sd[e0 + lane];            // row 'lane' of tile
  const int vDst = vSD & 0xffff;
  int vPerm = 0;
  if (lane < 16) vPerm = perm[e0 + w*16 + lane];
  const int pRow = __shfl(vPerm, lr);        // edge index of this wave's row lr

  // ---- issue dist loads (consumed first by the GEMM) ----
  const float* dp = dist + (long)pRow*64 + lq*8;
  fx4 d0 = *(const fx4*)(dp);
  fx4 d1 = *(const fx4*)(dp + 4);
  fx4 d2 = *(const fx4*)(dp + 32);
  fx4 d3 = *(const fx4*)(dp + 36);

  // ---- issue npj gather (src from sd; no dependent hop) ----
  bx4 rN[8];
#pragma unroll
  for (int i = 0; i < 8; ++i){
    int r = (lane >> 5) + 2*i;
    int s = __shfl(vSD, w*16 + r) >> 16;
    rN[i] = *(const bx4*)(npj + (long)s*128 + c32*4);
  }

  // ---- issue edge-row loads (consumed last -> longest latency slack) ----
  fx4 rE[8];
#pragma unroll
  for (int i = 0; i < 8; ++i){
    int r = (lane >> 5) + 2*i;
    int p = __shfl(vPerm, r);
    rE[i] = *(const fx4*)(edge_h + (long)p*128 + c32*4);
  }

  // ---- dist GEMM: M=16 (own rows), N=128, K=64; bias folded into acc init ----
  {
    bx8 a0 = cvt8(d0, d1);
    bx8 a1 = cvt8(d2, d3);
    fx4 facc[8];
#pragma unroll
    for (int n = 0; n < 8; ++n){
      float bdv = b_dist[n*16 + lr];
      facc[n] = (fx4){bdv, bdv, bdv, bdv};
    }
#pragma unroll
    for (int n = 0; n < 8; ++n){
      bx8 b = *(const bx8*)&WdP[((n*2 + 0)*64 + lane)*8];
      facc[n] = __builtin_amdgcn_mfma_f32_16x16x32_bf16(a0, b, facc[n], 0, 0, 0);
    }
#pragma unroll
    for (int n = 0; n < 8; ++n){
      bx8 b = *(const bx8*)&WdP[((n*2 + 1)*64 + lane)*8];
      facc[n] = __builtin_amdgcn_mfma_f32_16x16x32_bf16(a1, b, facc[n], 0, 0, 0);
    }
#pragma unroll
    for (int n = 0; n < 8; ++n)
#pragma unroll
      for (int j = 0; j < 4; ++j)
        sX[w][swz(lq*4 + j, n*16 + lr)] = f2bf(facc[n][j]);
  }

  // ---- m1 in-place: sX = npj[src] * sX  (own rows, same-wave dep) ----
#pragma unroll
  for (int i = 0; i < 8; ++i){
    int r = (lane >> 5) + 2*i;
    int xi = swz(r, c32*4);
    bx4 dp4 = *(const bx4*)&sX[w][xi];
    bx4 o;
#pragma unroll
    for (int k = 0; k < 4; ++k)
      o[k] = (short)f2bf( bf2f((unsigned short)rN[i][k]) * bf2f((unsigned short)dp4[k]) );
    *(bx4*)&sX[w][xi] = o;
  }

  // ---- stage edge rows bf16 -> sE (rE dies here) ----
#pragma unroll
  for (int i = 0; i < 8; ++i){
    int r = (lane >> 5) + 2*i;
    bx4 cv;
    cv[0]=(short)f2bf(rE[i][0]); cv[1]=(short)f2bf(rE[i][1]);
    cv[2]=(short)f2bf(rE[i][2]); cv[3]=(short)f2bf(rE[i][3]);
    *(bx4*)&sE[w][swz(r, c32*4)] = cv;
  }
  __syncthreads();   // the ONLY barrier: sX + sE complete across all waves

  // ---- segsum head mask (hoisted, reused by both halves) ----
  int up = __shfl_up(vDst, 1);
  bool head = (lane == 0) || (up != vDst);
  const unsigned long long mhead = __ballot(head);

  // ---- comb GEMM in two 32-col halves: cols [64w+32h, +32), K = 128(m1)+128(edge) ----
#pragma unroll
  for (int h = 0; h < 2; ++h){
    fx4 acc[4][2];
#pragma unroll
    for (int rt = 0; rt < 4; ++rt)
#pragma unroll
      for (int n = 0; n < 2; ++n) acc[rt][n] = (fx4){0.f,0.f,0.f,0.f};
#pragma unroll
    for (int ks = 0; ks < 4; ++ks){
      bx8 a[4], b[2];
#pragma unroll
      for (int rt = 0; rt < 4; ++rt)
        a[rt] = *(const bx8*)&sX[rt][swz(lr, ks*32 + lq*8)];
#pragma unroll
      for (int n = 0; n < 2; ++n)
        b[n] = *(const bx8*)&WctP[(((4*w + 2*h + n)*4 + ks)*64 + lane)*8];
#pragma unroll
      for (int rt = 0; rt < 4; ++rt)
#pragma unroll
        for (int n = 0; n < 2; ++n)
          acc[rt][n] = __builtin_amdgcn_mfma_f32_16x16x32_bf16(a[rt], b[n], acc[rt][n], 0, 0, 0);
    }
#pragma unroll
    for (int ks = 0; ks < 4; ++ks){
      bx8 a[4], b[2];
#pragma unroll
      for (int rt = 0; rt < 4; ++rt)
        a[rt] = *(const bx8*)&sE[rt][swz(lr, ks*32 + lq*8)];
#pragma unroll
      for (int n = 0; n < 2; ++n)
        b[n] = *(const bx8*)&WeffP[(((4*w + 2*h + n)*4 + ks)*64 + lane)*8];
#pragma unroll
      for (int rt = 0; rt < 4; ++rt)
#pragma unroll
        for (int n = 0; n < 2; ++n)
          acc[rt][n] = __builtin_amdgcn_mfma_f32_16x16x32_bf16(a[rt], b[n], acc[rt][n], 0, 0, 0);
    }

    // ---- + ceff, tanh ----
    float ce0 = ceff[(4*w + 2*h + 0)*16 + lr];
    float ce1 = ceff[(4*w + 2*h + 1)*16 + lr];
#pragma unroll
    for (int rt = 0; rt < 4; ++rt)
#pragma unroll
      for (int j = 0; j < 4; ++j){
        acc[rt][0][j] = fast_tanh(acc[rt][0][j] + ce0);
        acc[rt][1][j] = fast_tanh(acc[rt][1][j] + ce1);
      }

    // ---- register segmented column-sum over dst-runs (this half's 32 cols) ----
    unsigned long long m = mhead;
    while (m){
      int lo = __ffsll((unsigned long long)m) - 1;
      m &= m - 1;
      int hi = m ? (__ffsll((unsigned long long)m) - 1) : 64;
      int d  = __shfl(vDst, lo);
      float s0 = 0.f, s1 = 0.f;
#pragma unroll
      for (int rt = 0; rt < 4; ++rt)
#pragma unroll
        for (int j = 0; j < 4; ++j){
          int row = rt*16 + lq*4 + j;
          float msk = (row >= lo && row < hi) ? 1.f : 0.f;
          s0 += msk * acc[rt][0][j];
          s1 += msk * acc[rt][1][j];
        }
      s0 += __shfl_xor(s0, 16); s0 += __shfl_xor(s0, 32);
      s1 += __shfl_xor(s1, 16); s1 += __shfl_xor(s1, 32);
      if (lq < 2){
        float v = (lq == 0) ? s0 : s1;
        float* p = &hacc[(long)d*256 + (4*w + 2*h + lq)*16 + lr];
        if (lo == 0 || hi == 64) atomicAdd(p, v);   // run may extend past tile
        else                     *p = v;            // tile exclusively owns d
      }
    }
  }
}

// ---------------- K3: in-place row L2-normalize of d_out [20000][256] ----------------
__global__ __launch_bounds__(256)
void norm_kernel(float* __restrict__ h)
{
  int row  = blockIdx.x * 4 + (threadIdx.x >> 6);
  int lane = threadIdx.x & 63;
  fx4 v = *(const fx4*)&h[(long)row*256 + lane*4];
  float s = v[0]*v[0] + v[1]*v[1] + v[2]*v[2] + v[3]*v[3];
#pragma unroll
  for (int off = 32; off > 0; off >>= 1) s += __shfl_xor(s, off);
  float inv = (s > 0.f) ? 1.0f / sqrtf(s) : 0.f;
  v[0]*=inv; v[1]*=inv; v[2]*=inv; v[3]*=inv;
  *(fx4*)&h[(long)row*256 + lane*4] = v;
}

extern "C" void kernel_launch(void* const* d_in, const int* in_sizes, int n_in,
                              void* d_out, int out_size, void* d_ws, size_t ws_size,
                              hipStream_t stream)
{
  const float* node_h = (const float*)d_in[0];
  const float* edge_h = (const float*)d_in[1];
  const float* dist   = (const float*)d_in[2];
  const int*   src    = (const int*)d_in[3];
  const int*   dst    = (const int*)d_in[4];
  const float* W_node = (const float*)d_in[5];
  const float* b_node = (const float*)d_in[6];
  const float* W_edge = (const float*)d_in[7];
  const float* b_edge = (const float*)d_in[8];
  const float* W_dist = (const float*)d_in[9];
  const float* b_dist = (const float*)d_in[10];
  const float* W_comb = (const float*)d_in[11];

  char* ws = (char*)d_ws;
  unsigned short* npj   = (unsigned short*)ws;                  // 5,120,000
  unsigned short* WnP   = (unsigned short*)(ws + 5120000);      // +65,536
  unsigned short* WdP   = (unsigned short*)(ws + 5185536);      // +16,384
  unsigned short* WctP  = (unsigned short*)(ws + 5201920);      // +65,536
  unsigned short* WeffP = (unsigned short*)(ws + 5267456);      // +65,536
  float*          ceff  = (float*)(ws + 5332992);               // +1,024
  int* cnt  = (int*)(ws + 5334016);                             // +80,000
  int* fill = (int*)(ws + 5414016);                             // +80,000
  int* perm = (int*)(ws + 5494016);                             // +2,560,000
  int* sd   = (int*)(ws + 8054016);                             // +2,560,000
  int* bsum = (int*)(ws + 10614016);                            // +128 -> 10,614,144 B

  float* hacc = (float*)d_out;

  hipMemsetAsync(hacc, 0, (size_t)N_NODES * 256 * sizeof(float), stream);
  hipMemsetAsync(cnt, 0, (size_t)N_NODES * sizeof(int), stream);

  prep_all_kernel<<<417, 256, 0, stream>>>(W_node, W_dist, W_edge, W_comb, b_edge,
                                           WnP, WdP, WctP, WeffP, ceff);
  hist_kernel<<<2500, 256, 0, stream>>>(dst, cnt);
  scanA_kernel<<<20, 1024, 0, stream>>>(cnt, fill, bsum);
  scanB_kernel<<<1, 64, 0, stream>>>(bsum);
  scanC_kernel<<<20, 1024, 0, stream>>>(fill, bsum);
  scatter_kernel<<<2500, 256, 0, stream>>>(dst, src, fill, perm, sd);
  node_proj_kernel<<<1250, 64, 0, stream>>>(node_h, WnP, b_node, npj);
  edge_kernel<<<10000, 256, 0, stream>>>(edge_h, dist, perm, sd, npj,
                                         WdP, b_dist, WctP, WeffP, ceff, hacc);
  norm_kernel<<<5000, 256, 0, stream>>>(hacc);
}

// Round 15
// 345.233 us; speedup vs baseline: 1.1222x; 1.0072x over previous
//
#include <hip/hip_runtime.h>
#include <hip/hip_bf16.h>
#include <math.h>

typedef __attribute__((ext_vector_type(4))) float fx4;
typedef __attribute__((ext_vector_type(8))) short bx8;   // 8 bf16 (one MFMA A/B fragment)
typedef __attribute__((ext_vector_type(4))) short bx4;   // 4 bf16

#define DEV static __device__ __forceinline__
#define N_NODES 20000
#define N_EDGES 640000

DEV unsigned short f2bf(float f){
  __hip_bfloat16 h = __float2bfloat16(f);        // RNE hardware cvt
  return *(unsigned short*)&h;
}
DEV float bf2f(unsigned short h){
  union { float f; unsigned u; } a; a.u = ((unsigned)h) << 16;
  return a.f;
}
DEV float fast_tanh(float x){
  float t = __expf(2.0f * x);
  return 1.0f - 2.0f * __builtin_amdgcn_rcpf(t + 1.0f);
}
DEV bx8 cvt8(fx4 a, fx4 b){
  bx8 r;
  r[0]=(short)f2bf(a[0]); r[1]=(short)f2bf(a[1]); r[2]=(short)f2bf(a[2]); r[3]=(short)f2bf(a[3]);
  r[4]=(short)f2bf(b[0]); r[5]=(short)f2bf(b[1]); r[6]=(short)f2bf(b[2]); r[7]=(short)f2bf(b[3]);
  return r;
}
// T2 XOR swizzle: pitch 128 elems (256B), col ^ ((row&7)<<3); 16B-window preserving
DEV int swz(int r, int c){ return r*128 + (c ^ ((r & 7) << 3)); }

// ---------------- K0: ALL weight prep in one launch ----------------
// Fragment-packed layout: P[((nblk*KS + ks)*64 + lane)*8 + j]
//   = W[(ks*32 + (lane>>4)*8 + j)*N + (nblk*16 + (lane&15))]
__global__ __launch_bounds__(256)
void prep_all_kernel(const float* __restrict__ Wn, const float* __restrict__ Wd,
                     const float* __restrict__ We, const float* __restrict__ Wc,
                     const float* __restrict__ be,
                     unsigned short* __restrict__ WnP, unsigned short* __restrict__ WdP,
                     unsigned short* __restrict__ WctP, unsigned short* __restrict__ WeffP,
                     float* __restrict__ ceff)
{
  int t = blockIdx.x * 256 + threadIdx.x;
  if (t < 32768){
    int i=t, j=i&7, lane=(i>>3)&63, ks=(i>>9)&7, nblk=i>>12;
    WnP[i] = f2bf(Wn[(ks*32 + (lane>>4)*8 + j)*128 + nblk*16 + (lane&15)]);
  } else if (t < 40960){
    int i=t-32768, j=i&7, lane=(i>>3)&63, ks=(i>>9)&1, nblk=i>>10;
    WdP[i] = f2bf(Wd[(ks*32 + (lane>>4)*8 + j)*128 + nblk*16 + (lane&15)]);
  } else if (t < 73728){
    int i=t-40960, j=i&7, lane=(i>>3)&63, ks=(i>>9)&3, nblk=i>>11;
    WctP[i] = f2bf(Wc[(ks*32 + (lane>>4)*8 + j)*256 + nblk*16 + (lane&15)]);
  } else if (t < 106496){
    int i=t-73728, j=i&7, lane=(i>>3)&63, ks=(i>>9)&3, nblk=i>>11;
    int k = ks*32 + (lane>>4)*8 + j;
    int n = nblk*16 + (lane&15);
    float s = 0.f;
    for (int h = 0; h < 128; ++h)
      s += We[k*128 + h] * Wc[(128+h)*256 + n];      // Weff = We @ Wc_bot
    WeffP[i] = f2bf(s);
  } else if (t < 106752){
    int n = t - 106496;
    float s = 0.f;
    for (int h = 0; h < 128; ++h)
      s += be[h] * Wc[(128+h)*256 + n];              // ceff = be @ Wc_bot
    ceff[n] = s;
  }
}

// ---------------- counting sort by dst ----------------
__global__ __launch_bounds__(256)
void hist_kernel(const int* __restrict__ dst, int* __restrict__ cnt)
{
  int e = blockIdx.x * 256 + threadIdx.x;
  if (e < N_EDGES) atomicAdd(&cnt[dst[e]], 1);
}

// hierarchical exclusive scan: A (20 blocks local) -> B (scan 20 sums) -> C (add offsets)
__global__ __launch_bounds__(1024)
void scanA_kernel(const int* __restrict__ cnt, int* __restrict__ fill, int* __restrict__ bsum)
{
  __shared__ int wsum[16];
  const int t = threadIdx.x, lane = t & 63, w = t >> 6;
  int i = blockIdx.x * 1024 + t;
  int v = (i < N_NODES) ? cnt[i] : 0;
  int x = v;
#pragma unroll
  for (int s = 1; s < 64; s <<= 1){
    int u = __shfl_up(x, s, 64);
    if (lane >= s) x += u;
  }
  if (lane == 63) wsum[w] = x;
  __syncthreads();
  if (w == 0 && lane < 16){
    int y = wsum[lane];
#pragma unroll
    for (int s = 1; s < 16; s <<= 1){
      int u = __shfl_up(y, s, 64);
      if (lane >= s) y += u;
    }
    wsum[lane] = y;
  }
  __syncthreads();
  int wbase = (w == 0) ? 0 : wsum[w-1];
  int excl = wbase + x - v;
  if (i < N_NODES) fill[i] = excl;
  if (t == 1023) bsum[blockIdx.x] = excl + v;
}

__global__ __launch_bounds__(64)
void scanB_kernel(int* __restrict__ bsum)
{
  int lane = threadIdx.x;
  int v = (lane < 20) ? bsum[lane] : 0;
  int x = v;
#pragma unroll
  for (int s = 1; s < 32; s <<= 1){
    int u = __shfl_up(x, s, 64);
    if (lane >= s) x += u;
  }
  if (lane < 20) bsum[lane] = x - v;   // exclusive
}

__global__ __launch_bounds__(1024)
void scanC_kernel(int* __restrict__ fill, const int* __restrict__ bsum)
{
  int i = blockIdx.x * 1024 + threadIdx.x;
  if (i < N_NODES) fill[i] += bsum[blockIdx.x];
}

// scatter: perm[pos]=e ; sd[pos] = (src[e]<<16) | dst[e]   (both < 2^16)
__global__ __launch_bounds__(256)
void scatter_kernel(const int* __restrict__ dst, const int* __restrict__ src,
                    int* __restrict__ fill,
                    int* __restrict__ perm, int* __restrict__ sd)
{
  int e = blockIdx.x * 256 + threadIdx.x;
  if (e < N_EDGES){
    int d = dst[e];
    int pos = atomicAdd(&fill[d], 1);
    perm[pos] = e;
    sd[pos] = (src[e] << 16) | d;
  }
}

// ---------------- K1: node_proj = bf16(node_h @ W_node + b_node)  [20000][128] ----------------
__global__ __launch_bounds__(64)
void node_proj_kernel(const float* __restrict__ node_h, const unsigned short* __restrict__ WnP,
                      const float* __restrict__ b_node, unsigned short* __restrict__ npj)
{
  __shared__ unsigned short sN[16 * 264];
  const int lane = threadIdx.x;
  const int lr = lane & 15, lq = lane >> 4;
  const long r0 = (long)blockIdx.x * 16;

  const fx4* g = (const fx4*)(node_h + r0 * 256);
#pragma unroll
  for (int i = 0; i < 16; ++i){
    int idx = lane + 64 * i;
    int r = idx >> 6, c4 = idx & 63;
    fx4 v = g[idx];
    bx4 b;
    b[0]=(short)f2bf(v[0]); b[1]=(short)f2bf(v[1]); b[2]=(short)f2bf(v[2]); b[3]=(short)f2bf(v[3]);
    *(bx4*)&sN[r*264 + c4*4] = b;
  }
  __syncthreads();

  fx4 acc[8];
#pragma unroll
  for (int n = 0; n < 8; ++n) acc[n] = (fx4){0.f,0.f,0.f,0.f};
#pragma unroll
  for (int ks = 0; ks < 8; ++ks){
    bx8 a = *(const bx8*)&sN[lr*264 + ks*32 + lq*8];
#pragma unroll
    for (int n = 0; n < 8; ++n){
      bx8 b = *(const bx8*)&WnP[((n*8 + ks)*64 + lane)*8];
      acc[n] = __builtin_amdgcn_mfma_f32_16x16x32_bf16(a, b, acc[n], 0, 0, 0);
    }
  }
#pragma unroll
  for (int n = 0; n < 8; ++n){
    float bias = b_node[n*16 + lr];
#pragma unroll
    for (int j = 0; j < 4; ++j)
      npj[(r0 + lq*4 + j)*128 + n*16 + lr] = f2bf(acc[n][j] + bias);
  }
}

// ---------------- K2: fused pipeline over SORTED edges, 64 edges/block, 1 barrier ----------------
// out = tanh( m1 @ Wc_top + edge @ Weff + ceff ), Weff = We@Wc_bot (prep).
// sd[] packs (src<<16)|dst so src needs NO dependent gather.
// R15: hierarchical segsum — per-thread rt-group sums g0/g1 precomputed; per run,
// rt-windows are skipped / added whole / masked only at boundaries (lo,hi are
// wave-uniform -> cheap branches). Cuts ~60% of segsum VALU.
__global__ __launch_bounds__(256, 4)
void edge_kernel(const float* __restrict__ edge_h, const float* __restrict__ dist,
                 const int* __restrict__ perm, const int* __restrict__ sd,
                 const unsigned short* __restrict__ npj,
                 const unsigned short* __restrict__ WdP, const float* __restrict__ b_dist,
                 const unsigned short* __restrict__ WctP, const unsigned short* __restrict__ WeffP,
                 const float* __restrict__ ceff,
                 float* __restrict__ hacc)
{
  __shared__ unsigned short sX[4][16*128];   // m1 (bf16), per-wave chunk, swizzled
  __shared__ unsigned short sE[4][16*128];   // edge rows (bf16), per-wave chunk, swizzled

  const int tid  = threadIdx.x;
  const int w    = tid >> 6;
  const int lane = tid & 63;
  const int lr   = lane & 15;
  const int lq   = lane >> 4;
  const int c32  = lane & 31;              // column chunk (4 elems) for chunk-layout ops
  const long e0  = (long)blockIdx.x * 64;

  // ---- ids: sd gives (src,dst) for all 64 tile rows in one coalesced load ----
  const int vSD  = sd[e0 + lane];            // row 'lane' of tile
  const int vDst = vSD & 0xffff;
  int vPerm = 0;
  if (lane < 16) vPerm = perm[e0 + w*16 + lane];
  const int pRow = __shfl(vPerm, lr);        // edge index of this wave's row lr

  // ---- issue dist loads (consumed first by the GEMM) ----
  const float* dp = dist + (long)pRow*64 + lq*8;
  fx4 d0 = *(const fx4*)(dp);
  fx4 d1 = *(const fx4*)(dp + 4);
  fx4 d2 = *(const fx4*)(dp + 32);
  fx4 d3 = *(const fx4*)(dp + 36);

  // ---- issue npj gather (src from sd; no dependent hop) ----
  bx4 rN[8];
#pragma unroll
  for (int i = 0; i < 8; ++i){
    int r = (lane >> 5) + 2*i;
    int s = __shfl(vSD, w*16 + r) >> 16;
    rN[i] = *(const bx4*)(npj + (long)s*128 + c32*4);
  }

  // ---- issue edge-row loads (consumed last -> longest latency slack) ----
  fx4 rE[8];
#pragma unroll
  for (int i = 0; i < 8; ++i){
    int r = (lane >> 5) + 2*i;
    int p = __shfl(vPerm, r);
    rE[i] = *(const fx4*)(edge_h + (long)p*128 + c32*4);
  }

  // ---- dist GEMM: M=16 (own rows), N=128, K=64; bias folded into acc init ----
  {
    bx8 a0 = cvt8(d0, d1);
    bx8 a1 = cvt8(d2, d3);
    fx4 facc[8];
#pragma unroll
    for (int n = 0; n < 8; ++n){
      float bdv = b_dist[n*16 + lr];
      facc[n] = (fx4){bdv, bdv, bdv, bdv};
    }
#pragma unroll
    for (int n = 0; n < 8; ++n){
      bx8 b = *(const bx8*)&WdP[((n*2 + 0)*64 + lane)*8];
      facc[n] = __builtin_amdgcn_mfma_f32_16x16x32_bf16(a0, b, facc[n], 0, 0, 0);
    }
#pragma unroll
    for (int n = 0; n < 8; ++n){
      bx8 b = *(const bx8*)&WdP[((n*2 + 1)*64 + lane)*8];
      facc[n] = __builtin_amdgcn_mfma_f32_16x16x32_bf16(a1, b, facc[n], 0, 0, 0);
    }
#pragma unroll
    for (int n = 0; n < 8; ++n)
#pragma unroll
      for (int j = 0; j < 4; ++j)
        sX[w][swz(lq*4 + j, n*16 + lr)] = f2bf(facc[n][j]);
  }

  // ---- m1 in-place: sX = npj[src] * sX  (own rows, same-wave dep) ----
#pragma unroll
  for (int i = 0; i < 8; ++i){
    int r = (lane >> 5) + 2*i;
    int xi = swz(r, c32*4);
    bx4 dp4 = *(const bx4*)&sX[w][xi];
    bx4 o;
#pragma unroll
    for (int k = 0; k < 4; ++k)
      o[k] = (short)f2bf( bf2f((unsigned short)rN[i][k]) * bf2f((unsigned short)dp4[k]) );
    *(bx4*)&sX[w][xi] = o;
  }

  // ---- stage edge rows bf16 -> sE (rE dies here) ----
#pragma unroll
  for (int i = 0; i < 8; ++i){
    int r = (lane >> 5) + 2*i;
    bx4 cv;
    cv[0]=(short)f2bf(rE[i][0]); cv[1]=(short)f2bf(rE[i][1]);
    cv[2]=(short)f2bf(rE[i][2]); cv[3]=(short)f2bf(rE[i][3]);
    *(bx4*)&sE[w][swz(r, c32*4)] = cv;
  }
  __syncthreads();   // the ONLY barrier: sX + sE complete across all waves

  // ---- segsum head mask (hoisted, reused by both halves) ----
  int up = __shfl_up(vDst, 1);
  bool head = (lane == 0) || (up != vDst);
  const unsigned long long mhead = __ballot(head);

  // ---- comb GEMM in two 32-col halves: cols [64w+32h, +32), K = 128(m1)+128(edge) ----
#pragma unroll
  for (int h = 0; h < 2; ++h){
    fx4 acc[4][2];
#pragma unroll
    for (int rt = 0; rt < 4; ++rt)
#pragma unroll
      for (int n = 0; n < 2; ++n) acc[rt][n] = (fx4){0.f,0.f,0.f,0.f};
#pragma unroll
    for (int ks = 0; ks < 4; ++ks){
      bx8 a[4], b[2];
#pragma unroll
      for (int rt = 0; rt < 4; ++rt)
        a[rt] = *(const bx8*)&sX[rt][swz(lr, ks*32 + lq*8)];
#pragma unroll
      for (int n = 0; n < 2; ++n)
        b[n] = *(const bx8*)&WctP[(((4*w + 2*h + n)*4 + ks)*64 + lane)*8];
#pragma unroll
      for (int rt = 0; rt < 4; ++rt)
#pragma unroll
        for (int n = 0; n < 2; ++n)
          acc[rt][n] = __builtin_amdgcn_mfma_f32_16x16x32_bf16(a[rt], b[n], acc[rt][n], 0, 0, 0);
    }
#pragma unroll
    for (int ks = 0; ks < 4; ++ks){
      bx8 a[4], b[2];
#pragma unroll
      for (int rt = 0; rt < 4; ++rt)
        a[rt] = *(const bx8*)&sE[rt][swz(lr, ks*32 + lq*8)];
#pragma unroll
      for (int n = 0; n < 2; ++n)
        b[n] = *(const bx8*)&WeffP[(((4*w + 2*h + n)*4 + ks)*64 + lane)*8];
#pragma unroll
      for (int rt = 0; rt < 4; ++rt)
#pragma unroll
        for (int n = 0; n < 2; ++n)
          acc[rt][n] = __builtin_amdgcn_mfma_f32_16x16x32_bf16(a[rt], b[n], acc[rt][n], 0, 0, 0);
    }

    // ---- + ceff, tanh ----
    float ce0 = ceff[(4*w + 2*h + 0)*16 + lr];
    float ce1 = ceff[(4*w + 2*h + 1)*16 + lr];
#pragma unroll
    for (int rt = 0; rt < 4; ++rt)
#pragma unroll
      for (int j = 0; j < 4; ++j){
        acc[rt][0][j] = fast_tanh(acc[rt][0][j] + ce0);
        acc[rt][1][j] = fast_tanh(acc[rt][1][j] + ce1);
      }

    // ---- per-thread rt-group sums (shared across runs) ----
    float g0[4], g1[4];
#pragma unroll
    for (int rt = 0; rt < 4; ++rt){
      g0[rt] = (acc[rt][0][0] + acc[rt][0][1]) + (acc[rt][0][2] + acc[rt][0][3]);
      g1[rt] = (acc[rt][1][0] + acc[rt][1][1]) + (acc[rt][1][2] + acc[rt][1][3]);
    }

    // ---- hierarchical register segsum over dst-runs (this half's 32 cols) ----
    unsigned long long m = mhead;
    while (m){
      int lo = __ffsll((unsigned long long)m) - 1;
      m &= m - 1;
      int hi = m ? (__ffsll((unsigned long long)m) - 1) : 64;
      int d  = __shfl(vDst, lo);
      float s0 = 0.f, s1 = 0.f;
#pragma unroll
      for (int rt = 0; rt < 4; ++rt){
        const int wlo = rt*16, whi = rt*16 + 16;     // wave-uniform window
        if (hi <= wlo || lo >= whi) continue;        // uniform: disjoint -> skip
        if (lo <= wlo && whi <= hi){                 // uniform: fully contained
          s0 += g0[rt];
          s1 += g1[rt];
        } else {                                     // boundary window: per-j mask
#pragma unroll
          for (int j = 0; j < 4; ++j){
            int row = rt*16 + lq*4 + j;
            float msk = (row >= lo && row < hi) ? 1.f : 0.f;
            s0 += msk * acc[rt][0][j];
            s1 += msk * acc[rt][1][j];
          }
        }
      }
      s0 += __shfl_xor(s0, 16); s0 += __shfl_xor(s0, 32);
      s1 += __shfl_xor(s1, 16); s1 += __shfl_xor(s1, 32);
      if (lq < 2){
        float v = (lq == 0) ? s0 : s1;
        float* p = &hacc[(long)d*256 + (4*w + 2*h + lq)*16 + lr];
        if (lo == 0 || hi == 64) atomicAdd(p, v);   // run may extend past tile
        else                     *p = v;            // tile exclusively owns d
      }
    }
  }
}

// ---------------- K3: in-place row L2-normalize of d_out [20000][256] ----------------
__global__ __launch_bounds__(256)
void norm_kernel(float* __restrict__ h)
{
  int row  = blockIdx.x * 4 + (threadIdx.x >> 6);
  int lane = threadIdx.x & 63;
  fx4 v = *(const fx4*)&h[(long)row*256 + lane*4];
  float s = v[0]*v[0] + v[1]*v[1] + v[2]*v[2] + v[3]*v[3];
#pragma unroll
  for (int off = 32; off > 0; off >>= 1) s += __shfl_xor(s, off);
  float inv = (s > 0.f) ? 1.0f / sqrtf(s) : 0.f;
  v[0]*=inv; v[1]*=inv; v[2]*=inv; v[3]*=inv;
  *(fx4*)&h[(long)row*256 + lane*4] = v;
}

extern "C" void kernel_launch(void* const* d_in, const int* in_sizes, int n_in,
                              void* d_out, int out_size, void* d_ws, size_t ws_size,
                              hipStream_t stream)
{
  const float* node_h = (const float*)d_in[0];
  const float* edge_h = (const float*)d_in[1];
  const float* dist   = (const float*)d_in[2];
  const int*   src    = (const int*)d_in[3];
  const int*   dst    = (const int*)d_in[4];
  const float* W_node = (const float*)d_in[5];
  const float* b_node = (const float*)d_in[6];
  const float* W_edge = (const float*)d_in[7];
  const float* b_edge = (const float*)d_in[8];
  const float* W_dist = (const float*)d_in[9];
  const float* b_dist = (const float*)d_in[10];
  const float* W_comb = (const float*)d_in[11];

  char* ws = (char*)d_ws;
  unsigned short* npj   = (unsigned short*)ws;                  // 5,120,000
  unsigned short* WnP   = (unsigned short*)(ws + 5120000);      // +65,536
  unsigned short* WdP   = (unsigned short*)(ws + 5185536);      // +16,384
  unsigned short* WctP  = (unsigned short*)(ws + 5201920);      // +65,536
  unsigned short* WeffP = (unsigned short*)(ws + 5267456);      // +65,536
  float*          ceff  = (float*)(ws + 5332992);               // +1,024
  int* cnt  = (int*)(ws + 5334016);                             // +80,000
  int* fill = (int*)(ws + 5414016);                             // +80,000
  int* perm = (int*)(ws + 5494016);                             // +2,560,000
  int* sd   = (int*)(ws + 8054016);                             // +2,560,000
  int* bsum = (int*)(ws + 10614016);                            // +128 -> 10,614,144 B

  float* hacc = (float*)d_out;

  hipMemsetAsync(hacc, 0, (size_t)N_NODES * 256 * sizeof(float), stream);
  hipMemsetAsync(cnt, 0, (size_t)N_NODES * sizeof(int), stream);

  prep_all_kernel<<<417, 256, 0, stream>>>(W_node, W_dist, W_edge, W_comb, b_edge,
                                           WnP, WdP, WctP, WeffP, ceff);
  hist_kernel<<<2500, 256, 0, stream>>>(dst, cnt);
  scanA_kernel<<<20, 1024, 0, stream>>>(cnt, fill, bsum);
  scanB_kernel<<<1, 64, 0, stream>>>(bsum);
  scanC_kernel<<<20, 1024, 0, stream>>>(fill, bsum);
  scatter_kernel<<<2500, 256, 0, stream>>>(dst, src, fill, perm, sd);
  node_proj_kernel<<<1250, 64, 0, stream>>>(node_h, WnP, b_node, npj);
  edge_kernel<<<10000, 256, 0, stream>>>(edge_h, dist, perm, sd, npj,
                                         WdP, b_dist, WctP, WeffP, ceff, hacc);
  norm_kernel<<<5000, 256, 0, stream>>>(hacc);
}